// Round 12
// baseline (172.814 us; speedup 1.0000x reference)
//
#include <hip/hip_runtime.h>
#include <cstdint>

#define DEVI __device__ __forceinline__

using fx4 = __attribute__((ext_vector_type(4))) float;
using bf8 = __attribute__((ext_vector_type(8))) __bf16;
using s8v = __attribute__((ext_vector_type(8))) short;
using s4v = __attribute__((ext_vector_type(4))) short;
typedef unsigned short u16;
typedef unsigned int u32;

DEVI float b2f(u16 u) { return __builtin_bit_cast(float, (u32)u << 16); }
DEVI u16 f2b(float f) {
  u32 u = __builtin_bit_cast(u32, f);
  return (u16)((u + 0x7fffu + ((u >> 16) & 1u)) >> 16);
}

// async global->LDS, 16B per lane, dest = wave-uniform base + lane*16
#define GLOAD(g, l)                                                          \
  __builtin_amdgcn_global_load_lds(                                          \
      (const __attribute__((address_space(1))) unsigned int*)(g),            \
      (__attribute__((address_space(3))) unsigned int*)(l), 16, 0, 0)

// ---- weight prep: W0->bf16; wqk2=[Wq|Wq ; Wk|Wk]; WvT; Wc=Wsp@Wp, bc=Wsp@bp ----
__global__ __launch_bounds__(256) void prep(const float* __restrict__ W0,
                                            const float* __restrict__ Wq,
                                            const float* __restrict__ Wk,
                                            const float* __restrict__ Wv,
                                            const float* __restrict__ Wsp,
                                            const float* __restrict__ Wp,
                                            const float* __restrict__ bp,
                                            u16* __restrict__ w0b,
                                            u16* __restrict__ wqk2,
                                            u16* __restrict__ wvtb,
                                            u16* __restrict__ wcb,
                                            float* __restrict__ bcb) {
  __shared__ float row[256];
  __shared__ float red[4];
  const int y = blockIdx.y;
  const int t = threadIdx.x;
  if (y == 0) {
    const int i = blockIdx.x * 256 + t;
    if (i < 131072) w0b[i] = f2b(W0[i]);
  } else if (y == 1) {
    const int i = blockIdx.x * 256 + t;
    // wqk2 is [512][512] = 262144 elements (R7/R8 bug was a 2x overrun here).
    if (i < 262144) {
      const int r = i >> 9, c = i & 511;
      const float* src = (r < 256) ? Wq : Wk;
      wqk2[i] = f2b(src[((r & 255) << 8) + (c & 255)]);
    }
  } else if (y == 2) {
    const int i = blockIdx.x * 256 + t;
    if (i < 65536) {
      const int e = i >> 8, d = i & 255;
      wvtb[i] = f2b(Wv[d * 256 + e]);          // WvT[e,d] = Wv[d,e]
    }
  } else {
    if (blockIdx.x >= 256) return;
    const int o = blockIdx.x;
    row[t] = Wsp[o * 256 + t];
    __syncthreads();
    float acc = 0.f;
    for (int c = 0; c < 256; ++c) acc += row[c] * Wp[c * 256 + t];
    wcb[o * 256 + t] = f2b(acc);
    float pb = row[t] * bp[t];
#pragma unroll
    for (int m = 32; m > 0; m >>= 1) pb += __shfl_xor(pb, m);
    if ((t & 63) == 0) red[t >> 6] = pb;
    __syncthreads();
    if (t == 0) bcb[o] = red[0] + red[1] + red[2] + red[3];
  }
}

// ---- fused concat+1x1 conv: x0[b,n,o] = sum_c [fd;fs][b,c,n] * W0[o,c] ----
__global__ __launch_bounds__(512) void conv0f(const float* __restrict__ fd,
                                              const float* __restrict__ fs,
                                              const u16* __restrict__ w0b,
                                              u16* __restrict__ x0) {
  __shared__ u16 tmp[64 * 132];     // [c][n], pad 4
  __shared__ u16 ldsA[128 * 64];    // [n][c] chunk-swizzled
  __shared__ u16 ldsB[256 * 64];    // [o][c] linear (GLOAD)
  const int b = blockIdx.y;
  const int bm = blockIdx.x * 128;
  const int t = threadIdx.x;
  const int wid = t >> 6, lane = t & 63;
  const int wm = wid >> 2, wn = wid & 3;
  fx4 acc[4][4] = {};
  for (int kt = 0; kt < 512; kt += 64) {
#pragma unroll
    for (int i = 0; i < 4; ++i) {
      const int r = i * 64 + (t >> 3);
      const int kq = (t & 7) ^ (r & 7);
      GLOAD(w0b + (long)r * 512 + kt + kq * 8, &ldsB[i * 4096 + wid * 512]);
    }
    const float* src = ((kt < 256) ? fd : fs) + ((long)b * 256 + (kt & 255)) * 4096L + bm;
#pragma unroll
    for (int p = 0; p < 4; ++p) {
      const int c = (t >> 5) + p * 16;
      const int n4 = (t & 31) * 4;
      const fx4 v = *(const fx4*)&src[(long)c * 4096 + n4];
      s4v pk;
#pragma unroll
      for (int j = 0; j < 4; ++j) pk[j] = (short)f2b(v[j]);
      *(s4v*)&tmp[c * 132 + n4] = pk;
    }
    __syncthreads();
#pragma unroll
    for (int pass = 0; pass < 2; ++pass) {
      const int n = t & 127;
      const int g = (t >> 7) + pass * 4;
      s8v pk;
#pragma unroll
      for (int j = 0; j < 8; ++j) pk[j] = (short)tmp[(g * 8 + j) * 132 + n];
      *(s8v*)&ldsA[n * 64 + ((g ^ (n & 7)) * 8)] = pk;
    }
    __syncthreads();
#pragma unroll
    for (int ko = 0; ko < 2; ++ko) {
      bf8 af[4], bfr[4];
      const int kq = ko * 4 + (lane >> 4);
#pragma unroll
      for (int f = 0; f < 4; ++f) {
        const int ar = wm * 64 + f * 16 + (lane & 15);
        af[f] = *(const bf8*)&ldsA[ar * 64 + ((kq ^ (ar & 7)) * 8)];
        const int br = wn * 64 + f * 16 + (lane & 15);
        bfr[f] = *(const bf8*)&ldsB[br * 64 + ((kq ^ (br & 7)) * 8)];
      }
#pragma unroll
      for (int fm = 0; fm < 4; ++fm)
#pragma unroll
        for (int fn = 0; fn < 4; ++fn)
          acc[fm][fn] = __builtin_amdgcn_mfma_f32_16x16x32_bf16(af[fm], bfr[fn], acc[fm][fn], 0, 0, 0);
    }
    __syncthreads();
  }
#pragma unroll
  for (int fm = 0; fm < 4; ++fm) {
    const int m0 = wm * 64 + fm * 16 + ((lane >> 4) << 2);
#pragma unroll
    for (int fn = 0; fn < 4; ++fn) {
      const int o = wn * 64 + fn * 16 + (lane & 15);
#pragma unroll
      for (int r = 0; r < 4; ++r)
        x0[((long)b << 20) + (long)(bm + m0 + r) * 256 + o] = f2b(acc[fm][fn][r]);
    }
  }
}

// ---- bf16 NT GEMM: C[m,n] = sum_k A[m,k]*B[n,k] ----
// EPI: 0 normal; 1 = S2 hi/lo (rows<256) + diag partials;
//      4 = dual-gated residual write: od/os = (acc+bias[m])*g + residual.
//      (EPI=4 arg mapping: wqf=fd, wkf=fs, dpart=gd, poolpart=gs, bias=bc)
template <typename OT, int BIAS, int EPI>
__global__ __launch_bounds__(256) void gemm_nt(
    const u16* __restrict__ A, long sA, int lda,
    const u16* __restrict__ B, long sB, int ldb,
    OT* __restrict__ C, long sC, long sCs, int ldc,
    const float* __restrict__ bias, int Keff, int ksplit,
    const float* __restrict__ wqf, const float* __restrict__ wkf,
    float* __restrict__ dpart, float* __restrict__ poolpart) {
  __shared__ u16 ldsA[128 * 64];
  __shared__ u16 ldsB[128 * 64];
  const int z = blockIdx.z;
  const int bb = z / ksplit;
  const int ss = z - bb * ksplit;
  const int bm = blockIdx.x * 128;
  const int bn = blockIdx.y * 128;
  const u16* Ab = A + bb * sA + (long)ss * Keff + (long)bm * lda;
  const u16* Bb = B + bb * sB + (long)ss * Keff + (long)bn * ldb;
  const int tid = threadIdx.x;
  const int wid = tid >> 6;
  const int lane = tid & 63;
  const int wm = wid >> 1, wn = wid & 1;
  const int srow = tid >> 3;
  const int slot = tid & 7;

  fx4 acc[4][4] = {};
  for (int kt = 0; kt < Keff; kt += 64) {
#pragma unroll
    for (int i = 0; i < 4; ++i) {
      const int row = i * 32 + srow;
      const int kq = slot ^ (row & 7);
      GLOAD(Ab + (long)row * lda + kt + kq * 8, &ldsA[i * 2048 + wid * 512]);
      GLOAD(Bb + (long)row * ldb + kt + kq * 8, &ldsB[i * 2048 + wid * 512]);
    }
    __syncthreads();
#pragma unroll
    for (int ko = 0; ko < 2; ++ko) {
      bf8 af[4], bfr[4];
      const int kq = ko * 4 + (lane >> 4);
#pragma unroll
      for (int f = 0; f < 4; ++f) {
        const int ar = wm * 64 + f * 16 + (lane & 15);
        af[f] = *(const bf8*)&ldsA[ar * 64 + ((kq ^ (ar & 7)) * 8)];
        const int br = wn * 64 + f * 16 + (lane & 15);
        bfr[f] = *(const bf8*)&ldsB[br * 64 + ((kq ^ (br & 7)) * 8)];
      }
#pragma unroll
      for (int fm = 0; fm < 4; ++fm)
#pragma unroll
        for (int fn = 0; fn < 4; ++fn)
          acc[fm][fn] = __builtin_amdgcn_mfma_f32_16x16x32_bf16(af[fm], bfr[fn], acc[fm][fn], 0, 0, 0);
    }
    __syncthreads();
  }
  if constexpr (EPI == 1) {
    u16* S2b = (u16*)C + bb * sC;
    float dp[4][4];
#pragma unroll
    for (int fm = 0; fm < 4; ++fm)
#pragma unroll
      for (int r = 0; r < 4; ++r) dp[fm][r] = 0.f;
#pragma unroll
    for (int fm = 0; fm < 4; ++fm) {
      const int m0 = bm + wm * 64 + fm * 16 + ((lane >> 4) << 2);
#pragma unroll
      for (int fn = 0; fn < 4; ++fn) {
        const int n0 = bn + wn * 64 + fn * 16 + (lane & 15);
#pragma unroll
        for (int r = 0; r < 4; ++r) {
          const float v = acc[fm][fn][r];
          const int m = m0 + r;
          if (m < 256) {
            const u16 hi = f2b(v);
            S2b[(long)m * 512 + n0] = hi;
            S2b[(long)m * 512 + 256 + n0] = f2b(v - b2f(hi));
          }
          const float* wr = (m < 256) ? (wqf + (long)m * 256) : (wkf + (long)(m - 256) * 256);
          dp[fm][r] += v * wr[n0];
        }
      }
    }
#pragma unroll
    for (int fm = 0; fm < 4; ++fm)
#pragma unroll
      for (int r = 0; r < 4; ++r) {
        float s = dp[fm][r];
        s += __shfl_xor(s, 1); s += __shfl_xor(s, 2);
        s += __shfl_xor(s, 4); s += __shfl_xor(s, 8);
        if ((lane & 15) == 0) {
          const int m = bm + wm * 64 + fm * 16 + ((lane >> 4) << 2) + r;
          dpart[(long)(blockIdx.y * 2 + wn) * 4096 + bb * 512 + m] = s;
        }
      }
    return;
  }
  if constexpr (EPI == 4) {
    float* odp = (float*)C + bb * sC;
    float* osp = (float*)C + 8388608 + bb * sC;
    const float* fdp = wqf + bb * sC;
    const float* fsp = wkf + bb * sC;
#pragma unroll
    for (int fm = 0; fm < 4; ++fm) {
      const int m0 = bm + wm * 64 + fm * 16 + ((lane >> 4) << 2);
#pragma unroll
      for (int r = 0; r < 4; ++r) {
        const int m = m0 + r;
        const float bv = bias[m];
        const float g1 = dpart[bb * 256 + m];
        const float g2 = poolpart[bb * 256 + m];
        const long rowb = (long)m * ldc;
#pragma unroll
        for (int fn = 0; fn < 4; ++fn) {
          const int n0 = bn + wn * 64 + fn * 16 + (lane & 15);
          const float v = acc[fm][fn][r] + bv;
          odp[rowb + n0] = v * g1 + fdp[rowb + n0];
          osp[rowb + n0] = v * g2 + fsp[rowb + n0];
        }
      }
    }
    return;
  }
  OT* Cb = C + bb * sC + ss * sCs;
#pragma unroll
  for (int fm = 0; fm < 4; ++fm) {
    const int m0 = bm + wm * 64 + fm * 16 + ((lane >> 4) << 2);
#pragma unroll
    for (int fn = 0; fn < 4; ++fn) {
      const int n0 = bn + wn * 64 + fn * 16 + (lane & 15);
#pragma unroll
      for (int r = 0; r < 4; ++r) {
        float v = acc[fm][fn][r];
        if (BIAS == 2) v += bias[m0 + r];
        if constexpr (sizeof(OT) == 2) Cb[(long)(m0 + r) * ldc + n0] = (OT)f2b(v);
        else Cb[(long)(m0 + r) * ldc + n0] = v;
      }
    }
  }
}

// ---- fused depthwise 3x3 + transpose + column-sum partials ----
__global__ __launch_bounds__(256) void dwconvT(const u16* __restrict__ x,
                                               const float* __restrict__ wdw,
                                               u16* __restrict__ y,
                                               u16* __restrict__ yT,
                                               float* __restrict__ cspart) {
  __shared__ float w[9][256];
  __shared__ u16 tb2[32][264];
  __shared__ float psf[8][256];
  const int t = threadIdx.x;
  for (int i = t; i < 2304; i += 256) w[i % 9][i / 9] = wdw[i];
  const int b = blockIdx.x >> 7;
  const int strip = blockIdx.x & 127;
  const int n0 = strip * 32;
  const int h = n0 >> 6;
  const int w0 = n0 & 63;
  const int tc = (t & 31) * 8;
  const int tn = t >> 5;
  const u16* base = x + ((long)b << 20);
  float csl[8] = {0.f, 0.f, 0.f, 0.f, 0.f, 0.f, 0.f, 0.f};
  __syncthreads();
#pragma unroll
  for (int p = 0; p < 4; ++p) {
    const int nn = p * 8 + tn;
    const int ww = w0 + nn;
    float acc[8] = {0.f, 0.f, 0.f, 0.f, 0.f, 0.f, 0.f, 0.f};
#pragma unroll
    for (int ky = 0; ky < 3; ++ky) {
      const int hy = h + ky - 1;
      if ((unsigned)hy >= 64u) continue;
#pragma unroll
      for (int kx = 0; kx < 3; ++kx) {
        const int wx = ww + kx - 1;
        if ((unsigned)wx >= 64u) continue;
        const s8v v = *(const s8v*)&base[(((hy << 6) + wx) << 8) + tc];
        const int kk = ky * 3 + kx;
        const fx4 wa = *(const fx4*)&w[kk][tc];
        const fx4 wb = *(const fx4*)&w[kk][tc + 4];
#pragma unroll
        for (int j = 0; j < 4; ++j) {
          acc[j] += wa[j] * b2f((u16)v[j]);
          acc[4 + j] += wb[j] * b2f((u16)v[4 + j]);
        }
      }
    }
    s8v o;
#pragma unroll
    for (int j = 0; j < 8; ++j) {
      o[j] = (short)f2b(acc[j]);
      csl[j] += b2f((u16)o[j]);
    }
    *(s8v*)&y[((long)b << 20) + (long)((n0 + nn) << 8) + tc] = o;
    *(s8v*)&tb2[nn][tc] = o;
  }
#pragma unroll
  for (int j = 0; j < 8; ++j) psf[tn][tc + j] = csl[j];
  __syncthreads();
  const int cg = t >> 5;
  const int nn2 = t & 31;
  u16* yb = yT + ((long)b << 20);
#pragma unroll
  for (int cb = 0; cb < 256; cb += 8) {
    const int c = cb + cg;
    yb[(long)c * 4096 + n0 + nn2] = tb2[nn2][c];
  }
  if (t < 256) {
    float s = 0.f;
#pragma unroll
    for (int k = 0; k < 8; ++k) s += psf[k][t];
    cspart[(long)strip * 2048 + b * 256 + t] = s;
  }
}

// ---- sum Gram split-K partials (8) -> hi/lo bf16 G2 [B,256,512] ----
__global__ __launch_bounds__(256) void gsplit(const float* __restrict__ part,
                                              u16* __restrict__ G2) {
  const int i4 = (blockIdx.x * 256 + threadIdx.x) * 4;    // over 524288
  fx4 s = {0.f, 0.f, 0.f, 0.f};
#pragma unroll
  for (int ss = 0; ss < 8; ++ss) s += *(const fx4*)(part + (long)ss * 524288 + i4);
  const int b = i4 >> 16, rem = i4 & 65535, e = rem >> 8, c0 = rem & 255;
  u16* d = G2 + (long)b * 131072 + (long)e * 512 + c0;
  s4v hi, lo;
#pragma unroll
  for (int j = 0; j < 4; ++j) {
    u16 h = f2b(s[j]);
    hi[j] = (short)h;
    lo[j] = (short)f2b(s[j] - b2f(h));
  }
  *(s4v*)d = hi;
  *(s4v*)(d + 256) = lo;
}

// ---- fused araw + norm-scale + row softmax -> bf16 attn ----
// araw[c,d] = sum_e [Wk](c,e-hi/lo) S2(d,e-hi/lo); each wave owns 32 whole
// rows (acc[2][16]) so softmax is wave-local (shfl over 16-lane quarters).
__global__ __launch_bounds__(256) void arawsm(const u16* __restrict__ wqk2,
                                              const u16* __restrict__ S2,
                                              const float* __restrict__ dpart,
                                              u16* __restrict__ out) {
  __shared__ u16 ldsA[128 * 64];
  __shared__ u16 ldsB[256 * 64];
  __shared__ float rqv[256];
  __shared__ float rkv[128];
  const int bm = blockIdx.x;       // 0..1 (c-row tile)
  const int b  = blockIdx.y;       // batch
  const int t = threadIdx.x;
  const int wid = t >> 6, lane = t & 63;
  const int srow = t >> 3, slot = t & 7;
  {
    float dq = dpart[b * 512 + t] + dpart[4096 + b * 512 + t] +
               dpart[8192 + b * 512 + t] + dpart[12288 + b * 512 + t];
    rqv[t] = 1.f / fmaxf(sqrtf(fmaxf(dq, 0.f)), 1e-12f);
    if (t < 128) {
      const int ki = b * 512 + 256 + bm * 128 + t;
      float dk = dpart[ki] + dpart[4096 + ki] + dpart[8192 + ki] + dpart[12288 + ki];
      rkv[t] = 1.f / fmaxf(sqrtf(fmaxf(dk, 0.f)), 1e-12f);
    }
  }
  const u16* Ab = wqk2 + 131072 + (long)(bm * 128) * 512;   // Wk rows (hi|lo dup cols)
  const u16* Bb = S2 + (long)b * 131072;
  fx4 acc[2][16] = {};
  for (int kt = 0; kt < 512; kt += 64) {
#pragma unroll
    for (int i = 0; i < 4; ++i) {
      const int row = i * 32 + srow;
      const int kq = slot ^ (row & 7);
      GLOAD(Ab + (long)row * 512 + kt + kq * 8, &ldsA[i * 2048 + wid * 512]);
    }
#pragma unroll
    for (int i = 0; i < 8; ++i) {
      const int row = i * 32 + srow;
      const int kq = slot ^ (row & 7);
      GLOAD(Bb + (long)row * 512 + kt + kq * 8, &ldsB[i * 2048 + wid * 512]);
    }
    __syncthreads();
#pragma unroll
    for (int ko = 0; ko < 2; ++ko) {
      const int kq = ko * 4 + (lane >> 4);
      const int ar0 = wid * 32 + (lane & 15);
      const bf8 af0 = *(const bf8*)&ldsA[ar0 * 64 + ((kq ^ (ar0 & 7)) * 8)];
      const int ar1 = wid * 32 + 16 + (lane & 15);
      const bf8 af1 = *(const bf8*)&ldsA[ar1 * 64 + ((kq ^ (ar1 & 7)) * 8)];
#pragma unroll
      for (int fn = 0; fn < 16; ++fn) {
        const int br = fn * 16 + (lane & 15);
        const bf8 bfv = *(const bf8*)&ldsB[br * 64 + ((kq ^ (br & 7)) * 8)];
        acc[0][fn] = __builtin_amdgcn_mfma_f32_16x16x32_bf16(af0, bfv, acc[0][fn], 0, 0, 0);
        acc[1][fn] = __builtin_amdgcn_mfma_f32_16x16x32_bf16(af1, bfv, acc[1][fn], 0, 0, 0);
      }
    }
    __syncthreads();
  }
  // wave-local softmax: rows wid*32 + mi*16 + (lane>>4)*4 + j, cols fn*16 + (lane&15)
  u16* outb = out + (long)b * 65536;
  const int rq4 = lane >> 4;
#pragma unroll
  for (int mi = 0; mi < 2; ++mi) {
#pragma unroll
    for (int j = 0; j < 4; ++j) {
      const int rlocal = wid * 32 + mi * 16 + rq4 * 4 + j;
      const float rk = rkv[rlocal];
      float v[16];
      float mx = -3.4e38f;
#pragma unroll
      for (int fn = 0; fn < 16; ++fn) {
        const int d = fn * 16 + (lane & 15);
        v[fn] = acc[mi][fn][j] * rk * rqv[d];
        mx = fmaxf(mx, v[fn]);
      }
      mx = fmaxf(mx, __shfl_xor(mx, 1));
      mx = fmaxf(mx, __shfl_xor(mx, 2));
      mx = fmaxf(mx, __shfl_xor(mx, 4));
      mx = fmaxf(mx, __shfl_xor(mx, 8));
      float s = 0.f;
#pragma unroll
      for (int fn = 0; fn < 16; ++fn) { v[fn] = __expf(v[fn] - mx); s += v[fn]; }
      s += __shfl_xor(s, 1); s += __shfl_xor(s, 2);
      s += __shfl_xor(s, 4); s += __shfl_xor(s, 8);
      const float inv = 1.f / s;
      const long rowb = (long)(bm * 128 + rlocal) * 256;
#pragma unroll
      for (int fn = 0; fn < 16; ++fn)
        outb[rowb + fn * 16 + (lane & 15)] = f2b(v[fn] * inv);
    }
  }
}

// ---- fused wfin = Wc @ (attn @ Wv) per (e-tile, batch) block ----
__global__ __launch_bounds__(256) void mwfuse(const u16* __restrict__ attnb,
                                              const u16* __restrict__ wvtb,
                                              const u16* __restrict__ wcb,
                                              u16* __restrict__ wfin) {
  __shared__ u16 lds[25088];           // union, 50 KB
  const int M1OFF = 0;                 // m1T [64][264]
  const int A2OFF = 16896;             // Wc tile [256][32]
  const int B1OFF = 0;                 // phase1 attn [256][64]
  const int A1OFF = 16384;             // phase1 WvT [64][64]
  const int e0 = blockIdx.x * 64;
  const int b = blockIdx.y;
  const int t = threadIdx.x;
  const int wid = t >> 6, lane = t & 63;
  const int srow = t >> 3, slot = t & 7;
  const u16* attn = attnb + (long)b * 65536;

  fx4 acc[4][4] = {};
  for (int kt = 0; kt < 256; kt += 64) {
#pragma unroll
    for (int i = 0; i < 8; ++i) {
      const int row = i * 32 + srow;
      const int kq = slot ^ (row & 7);
      GLOAD(attn + (long)row * 256 + kt + kq * 8, &lds[B1OFF + i * 2048 + wid * 512]);
    }
#pragma unroll
    for (int i = 0; i < 2; ++i) {
      const int row = i * 32 + srow;
      const int kq = slot ^ (row & 7);
      GLOAD(wvtb + (long)(e0 + row) * 256 + kt + kq * 8, &lds[A1OFF + i * 2048 + wid * 512]);
    }
    __syncthreads();
#pragma unroll
    for (int ko = 0; ko < 2; ++ko) {
      bf8 af[4], bfr[4];
      const int kq = ko * 4 + (lane >> 4);
#pragma unroll
      for (int f = 0; f < 4; ++f) {
        const int ar = f * 16 + (lane & 15);
        af[f] = *(const bf8*)&lds[A1OFF + ar * 64 + ((kq ^ (ar & 7)) * 8)];
        const int br = wid * 64 + f * 16 + (lane & 15);
        bfr[f] = *(const bf8*)&lds[B1OFF + br * 64 + ((kq ^ (br & 7)) * 8)];
      }
#pragma unroll
      for (int fm = 0; fm < 4; ++fm)
#pragma unroll
        for (int fn = 0; fn < 4; ++fn)
          acc[fm][fn] = __builtin_amdgcn_mfma_f32_16x16x32_bf16(af[fm], bfr[fn], acc[fm][fn], 0, 0, 0);
    }
    __syncthreads();
  }
#pragma unroll
  for (int fm = 0; fm < 4; ++fm) {
    const int ep0 = fm * 16 + ((lane >> 4) << 2);
#pragma unroll
    for (int fn = 0; fn < 4; ++fn) {
      const int c = wid * 64 + fn * 16 + (lane & 15);
#pragma unroll
      for (int r = 0; r < 4; ++r)
        lds[M1OFF + (ep0 + r) * 264 + c] = f2b(acc[fm][fn][r]);
    }
  }
  __syncthreads();
  fx4 acc2[4][4] = {};
  for (int kt = 0; kt < 256; kt += 32) {
#pragma unroll
    for (int i = 0; i < 4; ++i) {
      const int row = i * 64 + (t >> 2);
      const int kq = (t & 3) ^ (row & 3);
      GLOAD(wcb + (long)row * 256 + kt + kq * 8, &lds[A2OFF + i * 2048 + wid * 512]);
    }
    __syncthreads();
    bf8 af[4], bfr[4];
    const int kq = lane >> 4;
#pragma unroll
    for (int f = 0; f < 4; ++f) {
      const int ar = wid * 64 + f * 16 + (lane & 15);
      af[f] = *(const bf8*)&lds[A2OFF + ar * 32 + ((kq ^ (ar & 3)) * 8)];
      const int br = f * 16 + (lane & 15);
      bfr[f] = *(const bf8*)&lds[M1OFF + br * 264 + kt + kq * 8];
    }
#pragma unroll
    for (int fm = 0; fm < 4; ++fm)
#pragma unroll
      for (int fn = 0; fn < 4; ++fn)
        acc2[fm][fn] = __builtin_amdgcn_mfma_f32_16x16x32_bf16(af[fm], bfr[fn], acc2[fm][fn], 0, 0, 0);
    __syncthreads();
  }
  u16* wf = wfin + (long)b * 65536;
#pragma unroll
  for (int fm = 0; fm < 4; ++fm) {
    const int o0 = wid * 64 + fm * 16 + ((lane >> 4) << 2);
#pragma unroll
    for (int fn = 0; fn < 4; ++fn) {
      const int e = e0 + fn * 16 + (lane & 15);
#pragma unroll
      for (int r = 0; r < 4; ++r)
        wf[(long)(o0 + r) * 256 + e] = f2b(acc2[fm][fn][r]);
    }
  }
}

// ---- SE gates from column-sum partials + wfin matvec + 2-layer MLP ----
__global__ __launch_bounds__(256) void sefuse(const float* __restrict__ cspart,
                                              const u16* __restrict__ wfin,
                                              const float* __restrict__ bcb,
                                              const float* __restrict__ w1d, const float* __restrict__ w2d,
                                              const float* __restrict__ w1s, const float* __restrict__ w2s,
                                              float* __restrict__ gd, float* __restrict__ gs) {
  const int b = blockIdx.x;
  const int t = threadIdx.x;
  __shared__ float xm[256], p[256], hd[16], hs[16];
  float s = 0.f;
#pragma unroll 8
  for (int sl = 0; sl < 128; ++sl) s += cspart[(long)sl * 2048 + b * 256 + t];
  xm[t] = s;
  __syncthreads();
  const u16* wf = wfin + (long)b * 65536 + (long)t * 256;
  float acc = 0.f;
#pragma unroll 4
  for (int e = 0; e < 256; e += 8) {
    const s8v w8 = *(const s8v*)&wf[e];
    const fx4 x0v = *(const fx4*)&xm[e];
    const fx4 x1v = *(const fx4*)&xm[e + 4];
#pragma unroll
    for (int j = 0; j < 4; ++j) {
      acc += b2f((u16)w8[j]) * x0v[j];
      acc += b2f((u16)w8[4 + j]) * x1v[j];
    }
  }
  p[t] = acc * (1.f / 4096.f) + bcb[t];
  __syncthreads();
  if (t < 16) {
    float ad = 0.f, as2 = 0.f;
    for (int j = 0; j < 256; ++j) {
      ad += w1d[t * 256 + j] * p[j];
      as2 += w1s[t * 256 + j] * p[j];
    }
    hd[t] = fmaxf(ad, 0.f);
    hs[t] = fmaxf(as2, 0.f);
  }
  __syncthreads();
  float ad = 0.f, as2 = 0.f;
#pragma unroll
  for (int r = 0; r < 16; ++r) {
    ad += w2d[t * 16 + r] * hd[r];
    as2 += w2s[t * 16 + r] * hs[r];
  }
  gd[b * 256 + t] = 1.f / (1.f + __expf(-ad));
  gs[b * 256 + t] = 1.f / (1.f + __expf(-as2));
}

extern "C" void kernel_launch(void* const* d_in, const int* in_sizes, int n_in,
                              void* d_out, int out_size, void* d_ws, size_t ws_size,
                              hipStream_t stream) {
  const float* fd  = (const float*)d_in[0];
  const float* fs  = (const float*)d_in[1];
  const float* W0  = (const float*)d_in[2];
  const float* Wdw = (const float*)d_in[3];
  const float* Wq  = (const float*)d_in[4];
  const float* Wk  = (const float*)d_in[5];
  const float* Wv  = (const float*)d_in[6];
  const float* Wp  = (const float*)d_in[7];
  const float* bp  = (const float*)d_in[8];
  const float* Wsp = (const float*)d_in[9];
  const float* w1d = (const float*)d_in[10];
  const float* w2d = (const float*)d_in[11];
  const float* w1s = (const float*)d_in[12];
  const float* w2s = (const float*)d_in[13];

  char* ws = (char*)d_ws;
  u16* x0b    = (u16*)(ws + 0);            // [B,N,256] 16.7MB; dead after dwconvT
  u16* xtb    = (u16*)(ws + 16777216);     // [B,N,256] 16.7MB; live to final gemm
  u16* xtT    = (u16*)(ws + 33554432);     // [B,256,N] 16.7MB; dead after gram
  float* part = (float*)(ws + 50331648);   // [8][B,256,256] fp32 16.7MB
  u16* G2     = (u16*)(ws + 67108864);     // [B,256,512] hi|lo 2.1MB
  u16* S2     = (u16*)(ws + 69206016);     // [B,256,512] hi|lo 2.1MB
  u16* attnb  = (u16*)(ws + 73400320);     // [B,256,256] 1MB
  u16* wfin   = (u16*)(ws + 74448896);     // [B,256,256] 1MB
  u16* w0b    = (u16*)(ws + 75497472);     // [256,512] 256KB
  u16* wqk2   = (u16*)(ws + 75759616);     // [512,512] 512KB
  u16* wvtb   = (u16*)(ws + 76283904);     // [256,256] 128KB
  u16* wcb    = (u16*)(ws + 76414976);     // [256,256] 128KB
  float* bcb  = (float*)(ws + 76546048);   // 256
  float* dpart = (float*)(ws + 76547072);  // [4][B*512] fp32 64KB
  float* cspart = (float*)(ws + 76611584); // [128][B*256] fp32 1MB
  float* gdp  = (float*)(ws + 77660160);   // [B,256]
  float* gsp  = (float*)(ws + 77668352);   // [B,256]
  float* od   = (float*)d_out;

  prep<<<dim3(2048, 4), 256, 0, stream>>>(W0, Wq, Wk, Wv, Wsp, Wp, bp,
                                          w0b, wqk2, wvtb, wcb, bcb);
  conv0f<<<dim3(32, 8), 512, 0, stream>>>(fd, fs, w0b, x0b);
  dwconvT<<<1024, 256, 0, stream>>>(x0b, Wdw, xtb, xtT, cspart);
  // Gram: G[b,c,e] = sum_n xtT[b,c,n] xtT[b,e,n]   M=N=256 K=4096, split-K x8
  gemm_nt<float, 0, 0><<<dim3(2, 2, 64), 256, 0, stream>>>(
      xtT, 1048576, 4096, xtT, 1048576, 4096,
      part, 65536, 524288, 256, nullptr, 512, 8, nullptr, nullptr, nullptr, nullptr);
  gsplit<<<512, 256, 0, stream>>>(part, G2);
  // SS = Wqk @ G  (M=512 N=256 K=512 hi|lo) with fused S2-split + diag partials
  gemm_nt<u16, 0, 1><<<dim3(4, 2, 8), 256, 0, stream>>>(
      wqk2, 0, 512, G2, 131072, 512, S2, 131072, 0, 512, nullptr, 512, 1,
      Wq, Wk, dpart, nullptr);
  // fused araw + softmax (wave-local rows)
  arawsm<<<dim3(2, 8), 256, 0, stream>>>(wqk2, S2, dpart, attnb);
  // wfin = Wc @ attn @ Wv (fused two-stage)
  mwfuse<<<dim3(4, 8), 256, 0, stream>>>(attnb, wvtb, wcb, wfin);
  // SE gates from linearity: pool = Wfin @ colsum(xt)/4096 + bc
  sefuse<<<8, 256, 0, stream>>>(cspart, wfin, bcb, w1d, w2d, w1s, w2s, gdp, gsp);
  // final: od/os[b,o,n] = (sum_e wfin[b,o,e] xt[b,n,e] + bc[o])*g + residual
  gemm_nt<float, 0, 4><<<dim3(2, 32, 8), 256, 0, stream>>>(
      wfin, 65536, 256, xtb, 1048576, 256, od, 1048576, 0, 4096, bcb, 256, 1,
      fd, fs, gdp, gsp);
}

// Round 13
// 164.256 us; speedup vs baseline: 1.0521x; 1.0521x over previous
//
#include <hip/hip_runtime.h>
#include <cstdint>

#define DEVI __device__ __forceinline__

using fx4 = __attribute__((ext_vector_type(4))) float;
using bf8 = __attribute__((ext_vector_type(8))) __bf16;
using s8v = __attribute__((ext_vector_type(8))) short;
using s4v = __attribute__((ext_vector_type(4))) short;
typedef unsigned short u16;
typedef unsigned int u32;

DEVI float b2f(u16 u) { return __builtin_bit_cast(float, (u32)u << 16); }
DEVI u16 f2b(float f) {
  u32 u = __builtin_bit_cast(u32, f);
  return (u16)((u + 0x7fffu + ((u >> 16) & 1u)) >> 16);
}

// async global->LDS, 16B per lane, dest = wave-uniform base + lane*16
#define GLOAD(g, l)                                                          \
  __builtin_amdgcn_global_load_lds(                                          \
      (const __attribute__((address_space(1))) unsigned int*)(g),            \
      (__attribute__((address_space(3))) unsigned int*)(l), 16, 0, 0)

// ---- weight prep: W0->bf16; wqk2=[Wq|Wq ; Wk|Wk]; WvT; Wc=Wsp@Wp, bc=Wsp@bp ----
__global__ __launch_bounds__(256) void prep(const float* __restrict__ W0,
                                            const float* __restrict__ Wq,
                                            const float* __restrict__ Wk,
                                            const float* __restrict__ Wv,
                                            const float* __restrict__ Wsp,
                                            const float* __restrict__ Wp,
                                            const float* __restrict__ bp,
                                            u16* __restrict__ w0b,
                                            u16* __restrict__ wqk2,
                                            u16* __restrict__ wvtb,
                                            u16* __restrict__ wcb,
                                            float* __restrict__ bcb) {
  __shared__ float row[256];
  __shared__ float red[4];
  const int y = blockIdx.y;
  const int t = threadIdx.x;
  if (y == 0) {
    const int i = blockIdx.x * 256 + t;
    if (i < 131072) w0b[i] = f2b(W0[i]);
  } else if (y == 1) {
    const int i = blockIdx.x * 256 + t;
    // wqk2 is [512][512] = 262144 elements (R7/R8 bug was a 2x overrun here).
    if (i < 262144) {
      const int r = i >> 9, c = i & 511;
      const float* src = (r < 256) ? Wq : Wk;
      wqk2[i] = f2b(src[((r & 255) << 8) + (c & 255)]);
    }
  } else if (y == 2) {
    const int i = blockIdx.x * 256 + t;
    if (i < 65536) {
      const int e = i >> 8, d = i & 255;
      wvtb[i] = f2b(Wv[d * 256 + e]);          // WvT[e,d] = Wv[d,e]
    }
  } else {
    if (blockIdx.x >= 256) return;
    const int o = blockIdx.x;
    row[t] = Wsp[o * 256 + t];
    __syncthreads();
    float acc = 0.f;
    for (int c = 0; c < 256; ++c) acc += row[c] * Wp[c * 256 + t];
    wcb[o * 256 + t] = f2b(acc);
    float pb = row[t] * bp[t];
#pragma unroll
    for (int m = 32; m > 0; m >>= 1) pb += __shfl_xor(pb, m);
    if ((t & 63) == 0) red[t >> 6] = pb;
    __syncthreads();
    if (t == 0) bcb[o] = red[0] + red[1] + red[2] + red[3];
  }
}

// ---- fused concat+1x1 conv: x0[b,n,o] = sum_c [fd;fs][b,c,n] * W0[o,c] ----
// 64-token M-tile, 512 blocks (2/CU), 8 waves each owning a 32-col B-slice.
__global__ __launch_bounds__(512) void conv0f(const float* __restrict__ fd,
                                              const float* __restrict__ fs,
                                              const u16* __restrict__ w0b,
                                              u16* __restrict__ x0) {
  __shared__ u16 tmp[64 * 68];      // [c][n] 64x64, pad 4
  __shared__ u16 ldsA[64 * 64];     // [n][c] chunk-swizzled
  __shared__ u16 ldsB[256 * 64];    // [o][c] linear (GLOAD)
  const int b = blockIdx.y;
  const int bm = blockIdx.x * 64;
  const int t = threadIdx.x;
  const int wid = t >> 6, lane = t & 63;   // wid 0..7
  fx4 acc[4][2] = {};
  for (int kt = 0; kt < 512; kt += 64) {
#pragma unroll
    for (int i = 0; i < 4; ++i) {
      const int r = i * 64 + (t >> 3);
      const int kq = (t & 7) ^ (r & 7);
      GLOAD(w0b + (long)r * 512 + kt + kq * 8, &ldsB[i * 4096 + wid * 512]);
    }
    const float* src = ((kt < 256) ? fd : fs) + ((long)b * 256 + (kt & 255)) * 4096L + bm;
#pragma unroll
    for (int p = 0; p < 2; ++p) {
      const int c = (t >> 4) + p * 32;
      const int n4 = (t & 15) * 4;
      const fx4 v = *(const fx4*)&src[(long)c * 4096 + n4];
      s4v pk;
#pragma unroll
      for (int j = 0; j < 4; ++j) pk[j] = (short)f2b(v[j]);
      *(s4v*)&tmp[c * 68 + n4] = pk;
    }
    __syncthreads();
    {
      const int n = t & 63;
      const int g = t >> 6;     // 0..7
      s8v pk;
#pragma unroll
      for (int j = 0; j < 8; ++j) pk[j] = (short)tmp[(g * 8 + j) * 68 + n];
      *(s8v*)&ldsA[n * 64 + ((g ^ (n & 7)) * 8)] = pk;
    }
    __syncthreads();
#pragma unroll
    for (int ko = 0; ko < 2; ++ko) {
      bf8 af[4], bfr[2];
      const int kq = ko * 4 + (lane >> 4);
#pragma unroll
      for (int f = 0; f < 4; ++f) {
        const int ar = f * 16 + (lane & 15);
        af[f] = *(const bf8*)&ldsA[ar * 64 + ((kq ^ (ar & 7)) * 8)];
      }
#pragma unroll
      for (int f = 0; f < 2; ++f) {
        const int br = wid * 32 + f * 16 + (lane & 15);
        bfr[f] = *(const bf8*)&ldsB[br * 64 + ((kq ^ (br & 7)) * 8)];
      }
#pragma unroll
      for (int fm = 0; fm < 4; ++fm)
#pragma unroll
        for (int fn = 0; fn < 2; ++fn)
          acc[fm][fn] = __builtin_amdgcn_mfma_f32_16x16x32_bf16(af[fm], bfr[fn], acc[fm][fn], 0, 0, 0);
    }
    __syncthreads();
  }
#pragma unroll
  for (int fm = 0; fm < 4; ++fm) {
    const int m0 = fm * 16 + ((lane >> 4) << 2);
#pragma unroll
    for (int fn = 0; fn < 2; ++fn) {
      const int o = wid * 32 + fn * 16 + (lane & 15);
#pragma unroll
      for (int r = 0; r < 4; ++r)
        x0[((long)b << 20) + (long)(bm + m0 + r) * 256 + o] = f2b(acc[fm][fn][r]);
    }
  }
}

// ---- bf16 NT GEMM: C[m,n] = sum_k A[m,k]*B[n,k] ----
// EPI: 0 normal; 1 = S2 hi/lo (rows<256) + diag partials;
//      4 = dual-gated residual write: od/os = (acc+bias[m])*g + residual.
//      (EPI=4 arg mapping: wqf=fd, wkf=fs, dpart=gd, poolpart=gs, bias=bc)
template <typename OT, int BIAS, int EPI>
__global__ __launch_bounds__(256) void gemm_nt(
    const u16* __restrict__ A, long sA, int lda,
    const u16* __restrict__ B, long sB, int ldb,
    OT* __restrict__ C, long sC, long sCs, int ldc,
    const float* __restrict__ bias, int Keff, int ksplit,
    const float* __restrict__ wqf, const float* __restrict__ wkf,
    float* __restrict__ dpart, float* __restrict__ poolpart) {
  __shared__ u16 ldsA[128 * 64];
  __shared__ u16 ldsB[128 * 64];
  const int z = blockIdx.z;
  const int bb = z / ksplit;
  const int ss = z - bb * ksplit;
  const int bm = blockIdx.x * 128;
  const int bn = blockIdx.y * 128;
  const u16* Ab = A + bb * sA + (long)ss * Keff + (long)bm * lda;
  const u16* Bb = B + bb * sB + (long)ss * Keff + (long)bn * ldb;
  const int tid = threadIdx.x;
  const int wid = tid >> 6;
  const int lane = tid & 63;
  const int wm = wid >> 1, wn = wid & 1;
  const int srow = tid >> 3;
  const int slot = tid & 7;

  fx4 acc[4][4] = {};
  for (int kt = 0; kt < Keff; kt += 64) {
#pragma unroll
    for (int i = 0; i < 4; ++i) {
      const int row = i * 32 + srow;
      const int kq = slot ^ (row & 7);
      GLOAD(Ab + (long)row * lda + kt + kq * 8, &ldsA[i * 2048 + wid * 512]);
      GLOAD(Bb + (long)row * ldb + kt + kq * 8, &ldsB[i * 2048 + wid * 512]);
    }
    __syncthreads();
#pragma unroll
    for (int ko = 0; ko < 2; ++ko) {
      bf8 af[4], bfr[4];
      const int kq = ko * 4 + (lane >> 4);
#pragma unroll
      for (int f = 0; f < 4; ++f) {
        const int ar = wm * 64 + f * 16 + (lane & 15);
        af[f] = *(const bf8*)&ldsA[ar * 64 + ((kq ^ (ar & 7)) * 8)];
        const int br = wn * 64 + f * 16 + (lane & 15);
        bfr[f] = *(const bf8*)&ldsB[br * 64 + ((kq ^ (br & 7)) * 8)];
      }
#pragma unroll
      for (int fm = 0; fm < 4; ++fm)
#pragma unroll
        for (int fn = 0; fn < 4; ++fn)
          acc[fm][fn] = __builtin_amdgcn_mfma_f32_16x16x32_bf16(af[fm], bfr[fn], acc[fm][fn], 0, 0, 0);
    }
    __syncthreads();
  }
  if constexpr (EPI == 1) {
    u16* S2b = (u16*)C + bb * sC;
    float dp[4][4];
#pragma unroll
    for (int fm = 0; fm < 4; ++fm)
#pragma unroll
      for (int r = 0; r < 4; ++r) dp[fm][r] = 0.f;
#pragma unroll
    for (int fm = 0; fm < 4; ++fm) {
      const int m0 = bm + wm * 64 + fm * 16 + ((lane >> 4) << 2);
#pragma unroll
      for (int fn = 0; fn < 4; ++fn) {
        const int n0 = bn + wn * 64 + fn * 16 + (lane & 15);
#pragma unroll
        for (int r = 0; r < 4; ++r) {
          const float v = acc[fm][fn][r];
          const int m = m0 + r;
          if (m < 256) {
            const u16 hi = f2b(v);
            S2b[(long)m * 512 + n0] = hi;
            S2b[(long)m * 512 + 256 + n0] = f2b(v - b2f(hi));
          }
          const float* wr = (m < 256) ? (wqf + (long)m * 256) : (wkf + (long)(m - 256) * 256);
          dp[fm][r] += v * wr[n0];
        }
      }
    }
#pragma unroll
    for (int fm = 0; fm < 4; ++fm)
#pragma unroll
      for (int r = 0; r < 4; ++r) {
        float s = dp[fm][r];
        s += __shfl_xor(s, 1); s += __shfl_xor(s, 2);
        s += __shfl_xor(s, 4); s += __shfl_xor(s, 8);
        if ((lane & 15) == 0) {
          const int m = bm + wm * 64 + fm * 16 + ((lane >> 4) << 2) + r;
          dpart[(long)(blockIdx.y * 2 + wn) * 4096 + bb * 512 + m] = s;
        }
      }
    return;
  }
  if constexpr (EPI == 4) {
    float* odp = (float*)C + bb * sC;
    float* osp = (float*)C + 8388608 + bb * sC;
    const float* fdp = wqf + bb * sC;
    const float* fsp = wkf + bb * sC;
#pragma unroll
    for (int fm = 0; fm < 4; ++fm) {
      const int m0 = bm + wm * 64 + fm * 16 + ((lane >> 4) << 2);
#pragma unroll
      for (int r = 0; r < 4; ++r) {
        const int m = m0 + r;
        const float bv = bias[m];
        const float g1 = dpart[bb * 256 + m];
        const float g2 = poolpart[bb * 256 + m];
        const long rowb = (long)m * ldc;
#pragma unroll
        for (int fn = 0; fn < 4; ++fn) {
          const int n0 = bn + wn * 64 + fn * 16 + (lane & 15);
          const float v = acc[fm][fn][r] + bv;
          odp[rowb + n0] = v * g1 + fdp[rowb + n0];
          osp[rowb + n0] = v * g2 + fsp[rowb + n0];
        }
      }
    }
    return;
  }
  OT* Cb = C + bb * sC + ss * sCs;
#pragma unroll
  for (int fm = 0; fm < 4; ++fm) {
    const int m0 = bm + wm * 64 + fm * 16 + ((lane >> 4) << 2);
#pragma unroll
    for (int fn = 0; fn < 4; ++fn) {
      const int n0 = bn + wn * 64 + fn * 16 + (lane & 15);
#pragma unroll
      for (int r = 0; r < 4; ++r) {
        float v = acc[fm][fn][r];
        if (BIAS == 2) v += bias[m0 + r];
        if constexpr (sizeof(OT) == 2) Cb[(long)(m0 + r) * ldc + n0] = (OT)f2b(v);
        else Cb[(long)(m0 + r) * ldc + n0] = v;
      }
    }
  }
}

// ---- fused depthwise 3x3 + transpose + column-sum partials ----
__global__ __launch_bounds__(256) void dwconvT(const u16* __restrict__ x,
                                               const float* __restrict__ wdw,
                                               u16* __restrict__ y,
                                               u16* __restrict__ yT,
                                               float* __restrict__ cspart) {
  __shared__ float w[9][256];
  __shared__ u16 tb2[32][264];
  __shared__ float psf[8][256];
  const int t = threadIdx.x;
  for (int i = t; i < 2304; i += 256) w[i % 9][i / 9] = wdw[i];
  const int b = blockIdx.x >> 7;
  const int strip = blockIdx.x & 127;
  const int n0 = strip * 32;
  const int h = n0 >> 6;
  const int w0 = n0 & 63;
  const int tc = (t & 31) * 8;
  const int tn = t >> 5;
  const u16* base = x + ((long)b << 20);
  float csl[8] = {0.f, 0.f, 0.f, 0.f, 0.f, 0.f, 0.f, 0.f};
  __syncthreads();
#pragma unroll
  for (int p = 0; p < 4; ++p) {
    const int nn = p * 8 + tn;
    const int ww = w0 + nn;
    float acc[8] = {0.f, 0.f, 0.f, 0.f, 0.f, 0.f, 0.f, 0.f};
#pragma unroll
    for (int ky = 0; ky < 3; ++ky) {
      const int hy = h + ky - 1;
      if ((unsigned)hy >= 64u) continue;
#pragma unroll
      for (int kx = 0; kx < 3; ++kx) {
        const int wx = ww + kx - 1;
        if ((unsigned)wx >= 64u) continue;
        const s8v v = *(const s8v*)&base[(((hy << 6) + wx) << 8) + tc];
        const int kk = ky * 3 + kx;
        const fx4 wa = *(const fx4*)&w[kk][tc];
        const fx4 wb = *(const fx4*)&w[kk][tc + 4];
#pragma unroll
        for (int j = 0; j < 4; ++j) {
          acc[j] += wa[j] * b2f((u16)v[j]);
          acc[4 + j] += wb[j] * b2f((u16)v[4 + j]);
        }
      }
    }
    s8v o;
#pragma unroll
    for (int j = 0; j < 8; ++j) {
      o[j] = (short)f2b(acc[j]);
      csl[j] += b2f((u16)o[j]);
    }
    *(s8v*)&y[((long)b << 20) + (long)((n0 + nn) << 8) + tc] = o;
    *(s8v*)&tb2[nn][tc] = o;
  }
#pragma unroll
  for (int j = 0; j < 8; ++j) psf[tn][tc + j] = csl[j];
  __syncthreads();
  const int cg = t >> 5;
  const int nn2 = t & 31;
  u16* yb = yT + ((long)b << 20);
#pragma unroll
  for (int cb = 0; cb < 256; cb += 8) {
    const int c = cb + cg;
    yb[(long)c * 4096 + n0 + nn2] = tb2[nn2][c];
  }
  if (t < 256) {
    float s = 0.f;
#pragma unroll
    for (int k = 0; k < 8; ++k) s += psf[k][t];
    cspart[(long)strip * 2048 + b * 256 + t] = s;
  }
}

// ---- sum Gram split-K partials (8) -> hi/lo bf16 G2 [B,256,512] ----
__global__ __launch_bounds__(256) void gsplit(const float* __restrict__ part,
                                              u16* __restrict__ G2) {
  const int i4 = (blockIdx.x * 256 + threadIdx.x) * 4;    // over 524288
  fx4 s = {0.f, 0.f, 0.f, 0.f};
#pragma unroll
  for (int ss = 0; ss < 8; ++ss) s += *(const fx4*)(part + (long)ss * 524288 + i4);
  const int b = i4 >> 16, rem = i4 & 65535, e = rem >> 8, c0 = rem & 255;
  u16* d = G2 + (long)b * 131072 + (long)e * 512 + c0;
  s4v hi, lo;
#pragma unroll
  for (int j = 0; j < 4; ++j) {
    u16 h = f2b(s[j]);
    hi[j] = (short)h;
    lo[j] = (short)f2b(s[j] - b2f(h));
  }
  *(s4v*)d = hi;
  *(s4v*)(d + 256) = lo;
}

// ---- finalize rinv from diag partials + row softmax over d -> bf16 attn ----
__global__ __launch_bounds__(256) void softmax_g2(const float* __restrict__ araw,
                                                  const float* __restrict__ dpart,
                                                  u16* __restrict__ out) {
  const int wid = threadIdx.x >> 6, lane = threadIdx.x & 63;
  const int t = threadIdx.x;
  const int b = blockIdx.x >> 6;
  __shared__ float rq[256];
  float dq = dpart[b * 512 + t] + dpart[4096 + b * 512 + t] +
             dpart[8192 + b * 512 + t] + dpart[12288 + b * 512 + t];
  rq[t] = 1.f / fmaxf(sqrtf(fmaxf(dq, 0.f)), 1e-12f);
  __syncthreads();
  const long row = (long)blockIdx.x * 4 + wid;   // b*256 + c
  const int c = (int)(row & 255);
  const int ki = b * 512 + 256 + c;
  float dk = dpart[ki] + dpart[4096 + ki] + dpart[8192 + ki] + dpart[12288 + ki];
  const float rk = 1.f / fmaxf(sqrtf(fmaxf(dk, 0.f)), 1e-12f);
  fx4 v = ((const fx4*)(araw + row * 256))[lane];
  v[0] *= rk * rq[lane * 4];     v[1] *= rk * rq[lane * 4 + 1];
  v[2] *= rk * rq[lane * 4 + 2]; v[3] *= rk * rq[lane * 4 + 3];
  float m = fmaxf(fmaxf(v[0], v[1]), fmaxf(v[2], v[3]));
#pragma unroll
  for (int o = 32; o > 0; o >>= 1) m = fmaxf(m, __shfl_xor(m, o));
  float e0 = __expf(v[0] - m), e1 = __expf(v[1] - m);
  float e2 = __expf(v[2] - m), e3 = __expf(v[3] - m);
  float s4 = e0 + e1 + e2 + e3;
#pragma unroll
  for (int o = 32; o > 0; o >>= 1) s4 += __shfl_xor(s4, o);
  const float inv = 1.f / s4;
  u16* op = out + row * 256 + lane * 4;
  op[0] = f2b(e0 * inv); op[1] = f2b(e1 * inv);
  op[2] = f2b(e2 * inv); op[3] = f2b(e3 * inv);
}

// ---- fused wfin = Wc @ (attn @ Wv) per (e-tile, batch) block ----
__global__ __launch_bounds__(256) void mwfuse(const u16* __restrict__ attnb,
                                              const u16* __restrict__ wvtb,
                                              const u16* __restrict__ wcb,
                                              u16* __restrict__ wfin) {
  __shared__ u16 lds[25088];           // union, 50 KB
  const int M1OFF = 0;                 // m1T [64][264]
  const int A2OFF = 16896;             // Wc tile [256][32]
  const int B1OFF = 0;                 // phase1 attn [256][64]
  const int A1OFF = 16384;             // phase1 WvT [64][64]
  const int e0 = blockIdx.x * 64;
  const int b = blockIdx.y;
  const int t = threadIdx.x;
  const int wid = t >> 6, lane = t & 63;
  const int srow = t >> 3, slot = t & 7;
  const u16* attn = attnb + (long)b * 65536;

  fx4 acc[4][4] = {};
  for (int kt = 0; kt < 256; kt += 64) {
#pragma unroll
    for (int i = 0; i < 8; ++i) {
      const int row = i * 32 + srow;
      const int kq = slot ^ (row & 7);
      GLOAD(attn + (long)row * 256 + kt + kq * 8, &lds[B1OFF + i * 2048 + wid * 512]);
    }
#pragma unroll
    for (int i = 0; i < 2; ++i) {
      const int row = i * 32 + srow;
      const int kq = slot ^ (row & 7);
      GLOAD(wvtb + (long)(e0 + row) * 256 + kt + kq * 8, &lds[A1OFF + i * 2048 + wid * 512]);
    }
    __syncthreads();
#pragma unroll
    for (int ko = 0; ko < 2; ++ko) {
      bf8 af[4], bfr[4];
      const int kq = ko * 4 + (lane >> 4);
#pragma unroll
      for (int f = 0; f < 4; ++f) {
        const int ar = f * 16 + (lane & 15);
        af[f] = *(const bf8*)&lds[A1OFF + ar * 64 + ((kq ^ (ar & 7)) * 8)];
        const int br = wid * 64 + f * 16 + (lane & 15);
        bfr[f] = *(const bf8*)&lds[B1OFF + br * 64 + ((kq ^ (br & 7)) * 8)];
      }
#pragma unroll
      for (int fm = 0; fm < 4; ++fm)
#pragma unroll
        for (int fn = 0; fn < 4; ++fn)
          acc[fm][fn] = __builtin_amdgcn_mfma_f32_16x16x32_bf16(af[fm], bfr[fn], acc[fm][fn], 0, 0, 0);
    }
    __syncthreads();
  }
#pragma unroll
  for (int fm = 0; fm < 4; ++fm) {
    const int ep0 = fm * 16 + ((lane >> 4) << 2);
#pragma unroll
    for (int fn = 0; fn < 4; ++fn) {
      const int c = wid * 64 + fn * 16 + (lane & 15);
#pragma unroll
      for (int r = 0; r < 4; ++r)
        lds[M1OFF + (ep0 + r) * 264 + c] = f2b(acc[fm][fn][r]);
    }
  }
  __syncthreads();
  fx4 acc2[4][4] = {};
  for (int kt = 0; kt < 256; kt += 32) {
#pragma unroll
    for (int i = 0; i < 4; ++i) {
      const int row = i * 64 + (t >> 2);
      const int kq = (t & 3) ^ (row & 3);
      GLOAD(wcb + (long)row * 256 + kt + kq * 8, &lds[A2OFF + i * 2048 + wid * 512]);
    }
    __syncthreads();
    bf8 af[4], bfr[4];
    const int kq = lane >> 4;
#pragma unroll
    for (int f = 0; f < 4; ++f) {
      const int ar = wid * 64 + f * 16 + (lane & 15);
      af[f] = *(const bf8*)&lds[A2OFF + ar * 32 + ((kq ^ (ar & 3)) * 8)];
      const int br = f * 16 + (lane & 15);
      bfr[f] = *(const bf8*)&lds[M1OFF + br * 264 + kt + kq * 8];
    }
#pragma unroll
    for (int fm = 0; fm < 4; ++fm)
#pragma unroll
      for (int fn = 0; fn < 4; ++fn)
        acc2[fm][fn] = __builtin_amdgcn_mfma_f32_16x16x32_bf16(af[fm], bfr[fn], acc2[fm][fn], 0, 0, 0);
    __syncthreads();
  }
  u16* wf = wfin + (long)b * 65536;
#pragma unroll
  for (int fm = 0; fm < 4; ++fm) {
    const int o0 = wid * 64 + fm * 16 + ((lane >> 4) << 2);
#pragma unroll
    for (int fn = 0; fn < 4; ++fn) {
      const int e = e0 + fn * 16 + (lane & 15);
#pragma unroll
      for (int r = 0; r < 4; ++r)
        wf[(long)(o0 + r) * 256 + e] = f2b(acc2[fm][fn][r]);
    }
  }
}

// ---- SE gates from column-sum partials + wfin matvec + 2-layer MLP ----
__global__ __launch_bounds__(256) void sefuse(const float* __restrict__ cspart,
                                              const u16* __restrict__ wfin,
                                              const float* __restrict__ bcb,
                                              const float* __restrict__ w1d, const float* __restrict__ w2d,
                                              const float* __restrict__ w1s, const float* __restrict__ w2s,
                                              float* __restrict__ gd, float* __restrict__ gs) {
  const int b = blockIdx.x;
  const int t = threadIdx.x;
  __shared__ float xm[256], p[256], hd[16], hs[16];
  float s = 0.f;
#pragma unroll 8
  for (int sl = 0; sl < 128; ++sl) s += cspart[(long)sl * 2048 + b * 256 + t];
  xm[t] = s;
  __syncthreads();
  const u16* wf = wfin + (long)b * 65536 + (long)t * 256;
  float acc = 0.f;
#pragma unroll 4
  for (int e = 0; e < 256; e += 8) {
    const s8v w8 = *(const s8v*)&wf[e];
    const fx4 x0v = *(const fx4*)&xm[e];
    const fx4 x1v = *(const fx4*)&xm[e + 4];
#pragma unroll
    for (int j = 0; j < 4; ++j) {
      acc += b2f((u16)w8[j]) * x0v[j];
      acc += b2f((u16)w8[4 + j]) * x1v[j];
    }
  }
  p[t] = acc * (1.f / 4096.f) + bcb[t];
  __syncthreads();
  if (t < 16) {
    float ad = 0.f, as2 = 0.f;
    for (int j = 0; j < 256; ++j) {
      ad += w1d[t * 256 + j] * p[j];
      as2 += w1s[t * 256 + j] * p[j];
    }
    hd[t] = fmaxf(ad, 0.f);
    hs[t] = fmaxf(as2, 0.f);
  }
  __syncthreads();
  float ad = 0.f, as2 = 0.f;
#pragma unroll
  for (int r = 0; r < 16; ++r) {
    ad += w2d[t * 16 + r] * hd[r];
    as2 += w2s[t * 16 + r] * hs[r];
  }
  gd[b * 256 + t] = 1.f / (1.f + __expf(-ad));
  gs[b * 256 + t] = 1.f / (1.f + __expf(-as2));
}

extern "C" void kernel_launch(void* const* d_in, const int* in_sizes, int n_in,
                              void* d_out, int out_size, void* d_ws, size_t ws_size,
                              hipStream_t stream) {
  const float* fd  = (const float*)d_in[0];
  const float* fs  = (const float*)d_in[1];
  const float* W0  = (const float*)d_in[2];
  const float* Wdw = (const float*)d_in[3];
  const float* Wq  = (const float*)d_in[4];
  const float* Wk  = (const float*)d_in[5];
  const float* Wv  = (const float*)d_in[6];
  const float* Wp  = (const float*)d_in[7];
  const float* bp  = (const float*)d_in[8];
  const float* Wsp = (const float*)d_in[9];
  const float* w1d = (const float*)d_in[10];
  const float* w2d = (const float*)d_in[11];
  const float* w1s = (const float*)d_in[12];
  const float* w2s = (const float*)d_in[13];

  char* ws = (char*)d_ws;
  u16* x0b    = (u16*)(ws + 0);            // [B,N,256] 16.7MB; dead after dwconvT
  u16* xtb    = (u16*)(ws + 16777216);     // [B,N,256] 16.7MB; live to final gemm
  u16* xtT    = (u16*)(ws + 33554432);     // [B,256,N] 16.7MB; dead after gram
  float* part = (float*)(ws + 50331648);   // [8][B,256,256] fp32 16.7MB
  u16* G2     = (u16*)(ws + 67108864);     // [B,256,512] hi|lo 2.1MB
  u16* S2     = (u16*)(ws + 69206016);     // [B,256,512] hi|lo 2.1MB
  float* araw = (float*)(ws + 71303168);   // [B,256,256] fp32 2.1MB
  u16* attnb  = (u16*)(ws + 73400320);     // [B,256,256] 1MB
  u16* wfin   = (u16*)(ws + 74448896);     // [B,256,256] 1MB
  u16* w0b    = (u16*)(ws + 75497472);     // [256,512] 256KB
  u16* wqk2   = (u16*)(ws + 75759616);     // [512,512] 512KB
  u16* wvtb   = (u16*)(ws + 76283904);     // [256,256] 128KB
  u16* wcb    = (u16*)(ws + 76414976);     // [256,256] 128KB
  float* bcb  = (float*)(ws + 76546048);   // 256
  float* dpart = (float*)(ws + 76547072);  // [4][B*512] fp32 64KB
  float* cspart = (float*)(ws + 76611584); // [128][B*256] fp32 1MB
  float* gdp  = (float*)(ws + 77660160);   // [B,256]
  float* gsp  = (float*)(ws + 77668352);   // [B,256]
  float* od   = (float*)d_out;

  prep<<<dim3(2048, 4), 256, 0, stream>>>(W0, Wq, Wk, Wv, Wsp, Wp, bp,
                                          w0b, wqk2, wvtb, wcb, bcb);
  conv0f<<<dim3(64, 8), 512, 0, stream>>>(fd, fs, w0b, x0b);
  dwconvT<<<1024, 256, 0, stream>>>(x0b, Wdw, xtb, xtT, cspart);
  // Gram: G[b,c,e] = sum_n xtT[b,c,n] xtT[b,e,n]   M=N=256 K=4096, split-K x8
  gemm_nt<float, 0, 0><<<dim3(2, 2, 64), 256, 0, stream>>>(
      xtT, 1048576, 4096, xtT, 1048576, 4096,
      part, 65536, 524288, 256, nullptr, 512, 8, nullptr, nullptr, nullptr, nullptr);
  gsplit<<<512, 256, 0, stream>>>(part, G2);
  // SS = Wqk @ G  (M=512 N=256 K=512 hi|lo) with fused S2-split + diag partials
  gemm_nt<u16, 0, 1><<<dim3(4, 2, 8), 256, 0, stream>>>(
      wqk2, 0, 512, G2, 131072, 512, S2, 131072, 0, 512, nullptr, 512, 1,
      Wq, Wk, dpart, nullptr);
  // araw = Wk G Wq^T: A=[Wk|Wk], B=S2 hi|lo   M=N=256 K=512
  gemm_nt<float, 0, 0><<<dim3(2, 2, 8), 256, 0, stream>>>(
      wqk2 + 131072, 0, 512, S2, 131072, 512, araw, 65536, 0, 256, nullptr, 512, 1,
      nullptr, nullptr, nullptr, nullptr);
  softmax_g2<<<512, 256, 0, stream>>>(araw, dpart, attnb);
  // wfin = Wc @ attn @ Wv (fused two-stage)
  mwfuse<<<dim3(4, 8), 256, 0, stream>>>(attnb, wvtb, wcb, wfin);
  // SE gates from linearity: pool = Wfin @ colsum(xt)/4096 + bc
  sefuse<<<8, 256, 0, stream>>>(cspart, wfin, bcb, w1d, w2d, w1s, w2s, gdp, gsp);
  // final: od/os[b,o,n] = (sum_e wfin[b,o,e] xt[b,n,e] + bc[o])*g + residual
  gemm_nt<float, 0, 4><<<dim3(2, 32, 8), 256, 0, stream>>>(
      wfin, 65536, 256, xtb, 1048576, 256, od, 1048576, 0, 4096, bcb, 256, 1,
      fd, fs, gdp, gsp);
}

// Round 14
// 160.473 us; speedup vs baseline: 1.0769x; 1.0236x over previous
//
#include <hip/hip_runtime.h>
#include <cstdint>

#define DEVI __device__ __forceinline__

using fx4 = __attribute__((ext_vector_type(4))) float;
using bf8 = __attribute__((ext_vector_type(8))) __bf16;
using s8v = __attribute__((ext_vector_type(8))) short;
using s4v = __attribute__((ext_vector_type(4))) short;
typedef unsigned short u16;
typedef unsigned int u32;

DEVI float b2f(u16 u) { return __builtin_bit_cast(float, (u32)u << 16); }
DEVI u16 f2b(float f) {
  u32 u = __builtin_bit_cast(u32, f);
  return (u16)((u + 0x7fffu + ((u >> 16) & 1u)) >> 16);
}

// async global->LDS, 16B per lane, dest = wave-uniform base + lane*16
#define GLOAD(g, l)                                                          \
  __builtin_amdgcn_global_load_lds(                                          \
      (const __attribute__((address_space(1))) unsigned int*)(g),            \
      (__attribute__((address_space(3))) unsigned int*)(l), 16, 0, 0)

// ---- weight prep: W0->bf16; wqk2=[Wq|Wq ; Wk|Wk]; WvT; Wc=Wsp@Wp, bc=Wsp@bp ----
__global__ __launch_bounds__(256) void prep(const float* __restrict__ W0,
                                            const float* __restrict__ Wq,
                                            const float* __restrict__ Wk,
                                            const float* __restrict__ Wv,
                                            const float* __restrict__ Wsp,
                                            const float* __restrict__ Wp,
                                            const float* __restrict__ bp,
                                            u16* __restrict__ w0b,
                                            u16* __restrict__ wqk2,
                                            u16* __restrict__ wvtb,
                                            u16* __restrict__ wcb,
                                            float* __restrict__ bcb) {
  __shared__ float row[256];
  __shared__ float red[4];
  const int y = blockIdx.y;
  const int t = threadIdx.x;
  if (y == 0) {
    const int i = blockIdx.x * 256 + t;
    if (i < 131072) w0b[i] = f2b(W0[i]);
  } else if (y == 1) {
    const int i = blockIdx.x * 256 + t;
    // wqk2 is [512][512] = 262144 elements (R7/R8 bug was a 2x overrun here).
    if (i < 262144) {
      const int r = i >> 9, c = i & 511;
      const float* src = (r < 256) ? Wq : Wk;
      wqk2[i] = f2b(src[((r & 255) << 8) + (c & 255)]);
    }
  } else if (y == 2) {
    const int i = blockIdx.x * 256 + t;
    if (i < 65536) {
      const int e = i >> 8, d = i & 255;
      wvtb[i] = f2b(Wv[d * 256 + e]);          // WvT[e,d] = Wv[d,e]
    }
  } else {
    if (blockIdx.x >= 256) return;
    const int o = blockIdx.x;
    row[t] = Wsp[o * 256 + t];
    __syncthreads();
    float acc = 0.f;
    for (int c = 0; c < 256; ++c) acc += row[c] * Wp[c * 256 + t];
    wcb[o * 256 + t] = f2b(acc);
    float pb = row[t] * bp[t];
#pragma unroll
    for (int m = 32; m > 0; m >>= 1) pb += __shfl_xor(pb, m);
    if ((t & 63) == 0) red[t >> 6] = pb;
    __syncthreads();
    if (t == 0) bcb[o] = red[0] + red[1] + red[2] + red[3];
  }
}

// ---- fused concat+1x1 conv: x0[b,n,o] = sum_c [fd;fs][b,c,n] * W0[o,c] ----
// 64-token M-tile, 512 blocks (2/CU), 8 waves each owning a 32-col B-slice.
__global__ __launch_bounds__(512) void conv0f(const float* __restrict__ fd,
                                              const float* __restrict__ fs,
                                              const u16* __restrict__ w0b,
                                              u16* __restrict__ x0) {
  __shared__ u16 tmp[64 * 68];      // [c][n] 64x64, pad 4
  __shared__ u16 ldsA[64 * 64];     // [n][c] chunk-swizzled
  __shared__ u16 ldsB[256 * 64];    // [o][c] linear (GLOAD)
  const int b = blockIdx.y;
  const int bm = blockIdx.x * 64;
  const int t = threadIdx.x;
  const int wid = t >> 6, lane = t & 63;   // wid 0..7
  fx4 acc[4][2] = {};
  for (int kt = 0; kt < 512; kt += 64) {
#pragma unroll
    for (int i = 0; i < 4; ++i) {
      const int r = i * 64 + (t >> 3);
      const int kq = (t & 7) ^ (r & 7);
      GLOAD(w0b + (long)r * 512 + kt + kq * 8, &ldsB[i * 4096 + wid * 512]);
    }
    const float* src = ((kt < 256) ? fd : fs) + ((long)b * 256 + (kt & 255)) * 4096L + bm;
#pragma unroll
    for (int p = 0; p < 2; ++p) {
      const int c = (t >> 4) + p * 32;
      const int n4 = (t & 15) * 4;
      const fx4 v = *(const fx4*)&src[(long)c * 4096 + n4];
      s4v pk;
#pragma unroll
      for (int j = 0; j < 4; ++j) pk[j] = (short)f2b(v[j]);
      *(s4v*)&tmp[c * 68 + n4] = pk;
    }
    __syncthreads();
    {
      const int n = t & 63;
      const int g = t >> 6;     // 0..7
      s8v pk;
#pragma unroll
      for (int j = 0; j < 8; ++j) pk[j] = (short)tmp[(g * 8 + j) * 68 + n];
      *(s8v*)&ldsA[n * 64 + ((g ^ (n & 7)) * 8)] = pk;
    }
    __syncthreads();
#pragma unroll
    for (int ko = 0; ko < 2; ++ko) {
      bf8 af[4], bfr[2];
      const int kq = ko * 4 + (lane >> 4);
#pragma unroll
      for (int f = 0; f < 4; ++f) {
        const int ar = f * 16 + (lane & 15);
        af[f] = *(const bf8*)&ldsA[ar * 64 + ((kq ^ (ar & 7)) * 8)];
      }
#pragma unroll
      for (int f = 0; f < 2; ++f) {
        const int br = wid * 32 + f * 16 + (lane & 15);
        bfr[f] = *(const bf8*)&ldsB[br * 64 + ((kq ^ (br & 7)) * 8)];
      }
#pragma unroll
      for (int fm = 0; fm < 4; ++fm)
#pragma unroll
        for (int fn = 0; fn < 2; ++fn)
          acc[fm][fn] = __builtin_amdgcn_mfma_f32_16x16x32_bf16(af[fm], bfr[fn], acc[fm][fn], 0, 0, 0);
    }
    __syncthreads();
  }
#pragma unroll
  for (int fm = 0; fm < 4; ++fm) {
    const int m0 = fm * 16 + ((lane >> 4) << 2);
#pragma unroll
    for (int fn = 0; fn < 2; ++fn) {
      const int o = wid * 32 + fn * 16 + (lane & 15);
#pragma unroll
      for (int r = 0; r < 4; ++r)
        x0[((long)b << 20) + (long)(bm + m0 + r) * 256 + o] = f2b(acc[fm][fn][r]);
    }
  }
}

// ---- bf16 NT GEMM: C[m,n] = sum_k A[m,k]*B[n,k] ----
// EPI: 0 normal; 1 = S2 hi/lo (rows<256) + diag partials;
//      4 = dual-gated residual write: od/os = (acc+bias[m])*g + residual.
//      (EPI=4 arg mapping: wqf=fd, wkf=fs, dpart=gd, poolpart=gs, bias=bc)
template <typename OT, int BIAS, int EPI>
__global__ __launch_bounds__(256) void gemm_nt(
    const u16* __restrict__ A, long sA, int lda,
    const u16* __restrict__ B, long sB, int ldb,
    OT* __restrict__ C, long sC, long sCs, int ldc,
    const float* __restrict__ bias, int Keff, int ksplit,
    const float* __restrict__ wqf, const float* __restrict__ wkf,
    float* __restrict__ dpart, float* __restrict__ poolpart) {
  __shared__ u16 ldsA[128 * 64];
  __shared__ u16 ldsB[128 * 64];
  const int z = blockIdx.z;
  const int bb = z / ksplit;
  const int ss = z - bb * ksplit;
  const int bm = blockIdx.x * 128;
  const int bn = blockIdx.y * 128;
  const u16* Ab = A + bb * sA + (long)ss * Keff + (long)bm * lda;
  const u16* Bb = B + bb * sB + (long)ss * Keff + (long)bn * ldb;
  const int tid = threadIdx.x;
  const int wid = tid >> 6;
  const int lane = tid & 63;
  const int wm = wid >> 1, wn = wid & 1;
  const int srow = tid >> 3;
  const int slot = tid & 7;

  fx4 acc[4][4] = {};
  for (int kt = 0; kt < Keff; kt += 64) {
#pragma unroll
    for (int i = 0; i < 4; ++i) {
      const int row = i * 32 + srow;
      const int kq = slot ^ (row & 7);
      GLOAD(Ab + (long)row * lda + kt + kq * 8, &ldsA[i * 2048 + wid * 512]);
      GLOAD(Bb + (long)row * ldb + kt + kq * 8, &ldsB[i * 2048 + wid * 512]);
    }
    __syncthreads();
#pragma unroll
    for (int ko = 0; ko < 2; ++ko) {
      bf8 af[4], bfr[4];
      const int kq = ko * 4 + (lane >> 4);
#pragma unroll
      for (int f = 0; f < 4; ++f) {
        const int ar = wm * 64 + f * 16 + (lane & 15);
        af[f] = *(const bf8*)&ldsA[ar * 64 + ((kq ^ (ar & 7)) * 8)];
        const int br = wn * 64 + f * 16 + (lane & 15);
        bfr[f] = *(const bf8*)&ldsB[br * 64 + ((kq ^ (br & 7)) * 8)];
      }
#pragma unroll
      for (int fm = 0; fm < 4; ++fm)
#pragma unroll
        for (int fn = 0; fn < 4; ++fn)
          acc[fm][fn] = __builtin_amdgcn_mfma_f32_16x16x32_bf16(af[fm], bfr[fn], acc[fm][fn], 0, 0, 0);
    }
    __syncthreads();
  }
  if constexpr (EPI == 1) {
    u16* S2b = (u16*)C + bb * sC;
    float dp[4][4];
#pragma unroll
    for (int fm = 0; fm < 4; ++fm)
#pragma unroll
      for (int r = 0; r < 4; ++r) dp[fm][r] = 0.f;
#pragma unroll
    for (int fm = 0; fm < 4; ++fm) {
      const int m0 = bm + wm * 64 + fm * 16 + ((lane >> 4) << 2);
#pragma unroll
      for (int fn = 0; fn < 4; ++fn) {
        const int n0 = bn + wn * 64 + fn * 16 + (lane & 15);
#pragma unroll
        for (int r = 0; r < 4; ++r) {
          const float v = acc[fm][fn][r];
          const int m = m0 + r;
          if (m < 256) {
            const u16 hi = f2b(v);
            S2b[(long)m * 512 + n0] = hi;
            S2b[(long)m * 512 + 256 + n0] = f2b(v - b2f(hi));
          }
          const float* wr = (m < 256) ? (wqf + (long)m * 256) : (wkf + (long)(m - 256) * 256);
          dp[fm][r] += v * wr[n0];
        }
      }
    }
#pragma unroll
    for (int fm = 0; fm < 4; ++fm)
#pragma unroll
      for (int r = 0; r < 4; ++r) {
        float s = dp[fm][r];
        s += __shfl_xor(s, 1); s += __shfl_xor(s, 2);
        s += __shfl_xor(s, 4); s += __shfl_xor(s, 8);
        if ((lane & 15) == 0) {
          const int m = bm + wm * 64 + fm * 16 + ((lane >> 4) << 2) + r;
          dpart[(long)(blockIdx.y * 2 + wn) * 4096 + bb * 512 + m] = s;
        }
      }
    return;
  }
  if constexpr (EPI == 4) {
    float* odp = (float*)C + bb * sC;
    float* osp = (float*)C + 8388608 + bb * sC;
    const float* fdp = wqf + bb * sC;
    const float* fsp = wkf + bb * sC;
#pragma unroll
    for (int fm = 0; fm < 4; ++fm) {
      const int m0 = bm + wm * 64 + fm * 16 + ((lane >> 4) << 2);
#pragma unroll
      for (int r = 0; r < 4; ++r) {
        const int m = m0 + r;
        const float bv = bias[m];
        const float g1 = dpart[bb * 256 + m];
        const float g2 = poolpart[bb * 256 + m];
        const long rowb = (long)m * ldc;
#pragma unroll
        for (int fn = 0; fn < 4; ++fn) {
          const int n0 = bn + wn * 64 + fn * 16 + (lane & 15);
          const float v = acc[fm][fn][r] + bv;
          odp[rowb + n0] = v * g1 + fdp[rowb + n0];
          osp[rowb + n0] = v * g2 + fsp[rowb + n0];
        }
      }
    }
    return;
  }
  OT* Cb = C + bb * sC + ss * sCs;
#pragma unroll
  for (int fm = 0; fm < 4; ++fm) {
    const int m0 = bm + wm * 64 + fm * 16 + ((lane >> 4) << 2);
#pragma unroll
    for (int fn = 0; fn < 4; ++fn) {
      const int n0 = bn + wn * 64 + fn * 16 + (lane & 15);
#pragma unroll
      for (int r = 0; r < 4; ++r) {
        float v = acc[fm][fn][r];
        if (BIAS == 2) v += bias[m0 + r];
        if constexpr (sizeof(OT) == 2) Cb[(long)(m0 + r) * ldc + n0] = (OT)f2b(v);
        else Cb[(long)(m0 + r) * ldc + n0] = v;
      }
    }
  }
}

// ---- fused depthwise 3x3 + transpose + column-sum partials ----
__global__ __launch_bounds__(256) void dwconvT(const u16* __restrict__ x,
                                               const float* __restrict__ wdw,
                                               u16* __restrict__ y,
                                               u16* __restrict__ yT,
                                               float* __restrict__ cspart) {
  __shared__ float w[9][256];
  __shared__ u16 tb2[32][264];
  __shared__ float psf[8][256];
  const int t = threadIdx.x;
  for (int i = t; i < 2304; i += 256) w[i % 9][i / 9] = wdw[i];
  const int b = blockIdx.x >> 7;
  const int strip = blockIdx.x & 127;
  const int n0 = strip * 32;
  const int h = n0 >> 6;
  const int w0 = n0 & 63;
  const int tc = (t & 31) * 8;
  const int tn = t >> 5;
  const u16* base = x + ((long)b << 20);
  float csl[8] = {0.f, 0.f, 0.f, 0.f, 0.f, 0.f, 0.f, 0.f};
  __syncthreads();
#pragma unroll
  for (int p = 0; p < 4; ++p) {
    const int nn = p * 8 + tn;
    const int ww = w0 + nn;
    float acc[8] = {0.f, 0.f, 0.f, 0.f, 0.f, 0.f, 0.f, 0.f};
#pragma unroll
    for (int ky = 0; ky < 3; ++ky) {
      const int hy = h + ky - 1;
      if ((unsigned)hy >= 64u) continue;
#pragma unroll
      for (int kx = 0; kx < 3; ++kx) {
        const int wx = ww + kx - 1;
        if ((unsigned)wx >= 64u) continue;
        const s8v v = *(const s8v*)&base[(((hy << 6) + wx) << 8) + tc];
        const int kk = ky * 3 + kx;
        const fx4 wa = *(const fx4*)&w[kk][tc];
        const fx4 wb = *(const fx4*)&w[kk][tc + 4];
#pragma unroll
        for (int j = 0; j < 4; ++j) {
          acc[j] += wa[j] * b2f((u16)v[j]);
          acc[4 + j] += wb[j] * b2f((u16)v[4 + j]);
        }
      }
    }
    s8v o;
#pragma unroll
    for (int j = 0; j < 8; ++j) {
      o[j] = (short)f2b(acc[j]);
      csl[j] += b2f((u16)o[j]);
    }
    *(s8v*)&y[((long)b << 20) + (long)((n0 + nn) << 8) + tc] = o;
    *(s8v*)&tb2[nn][tc] = o;
  }
#pragma unroll
  for (int j = 0; j < 8; ++j) psf[tn][tc + j] = csl[j];
  __syncthreads();
  const int cg = t >> 5;
  const int nn2 = t & 31;
  u16* yb = yT + ((long)b << 20);
#pragma unroll
  for (int cb = 0; cb < 256; cb += 8) {
    const int c = cb + cg;
    yb[(long)c * 4096 + n0 + nn2] = tb2[nn2][c];
  }
  if (t < 256) {
    float s = 0.f;
#pragma unroll
    for (int k = 0; k < 8; ++k) s += psf[k][t];
    cspart[(long)strip * 2048 + b * 256 + t] = s;
  }
}

// ---- sum Gram split-K partials (8) -> hi/lo bf16 G2 [B,256,512] ----
__global__ __launch_bounds__(256) void gsplit(const float* __restrict__ part,
                                              u16* __restrict__ G2) {
  const int i4 = (blockIdx.x * 256 + threadIdx.x) * 4;    // over 524288
  fx4 s = {0.f, 0.f, 0.f, 0.f};
#pragma unroll
  for (int ss = 0; ss < 8; ++ss) s += *(const fx4*)(part + (long)ss * 524288 + i4);
  const int b = i4 >> 16, rem = i4 & 65535, e = rem >> 8, c0 = rem & 255;
  u16* d = G2 + (long)b * 131072 + (long)e * 512 + c0;
  s4v hi, lo;
#pragma unroll
  for (int j = 0; j < 4; ++j) {
    u16 h = f2b(s[j]);
    hi[j] = (short)h;
    lo[j] = (short)f2b(s[j] - b2f(h));
  }
  *(s4v*)d = hi;
  *(s4v*)(d + 256) = lo;
}

// ---- finalize rinv + sum araw split-K pair + row softmax -> bf16 attn ----
__global__ __launch_bounds__(256) void softmax_g2(const float* __restrict__ araw,
                                                  const float* __restrict__ dpart,
                                                  u16* __restrict__ out) {
  const int wid = threadIdx.x >> 6, lane = threadIdx.x & 63;
  const int t = threadIdx.x;
  const int b = blockIdx.x >> 6;
  __shared__ float rq[256];
  float dq = dpart[b * 512 + t] + dpart[4096 + b * 512 + t] +
             dpart[8192 + b * 512 + t] + dpart[12288 + b * 512 + t];
  rq[t] = 1.f / fmaxf(sqrtf(fmaxf(dq, 0.f)), 1e-12f);
  __syncthreads();
  const long row = (long)blockIdx.x * 4 + wid;   // b*256 + c
  const int c = (int)(row & 255);
  const int ki = b * 512 + 256 + c;
  float dk = dpart[ki] + dpart[4096 + ki] + dpart[8192 + ki] + dpart[12288 + ki];
  const float rk = 1.f / fmaxf(sqrtf(fmaxf(dk, 0.f)), 1e-12f);
  fx4 v = ((const fx4*)(araw + row * 256))[lane] +
          ((const fx4*)(araw + 524288 + row * 256))[lane];
  v[0] *= rk * rq[lane * 4];     v[1] *= rk * rq[lane * 4 + 1];
  v[2] *= rk * rq[lane * 4 + 2]; v[3] *= rk * rq[lane * 4 + 3];
  float m = fmaxf(fmaxf(v[0], v[1]), fmaxf(v[2], v[3]));
#pragma unroll
  for (int o = 32; o > 0; o >>= 1) m = fmaxf(m, __shfl_xor(m, o));
  float e0 = __expf(v[0] - m), e1 = __expf(v[1] - m);
  float e2 = __expf(v[2] - m), e3 = __expf(v[3] - m);
  float s4 = e0 + e1 + e2 + e3;
#pragma unroll
  for (int o = 32; o > 0; o >>= 1) s4 += __shfl_xor(s4, o);
  const float inv = 1.f / s4;
  u16* op = out + row * 256 + lane * 4;
  op[0] = f2b(e0 * inv); op[1] = f2b(e1 * inv);
  op[2] = f2b(e2 * inv); op[3] = f2b(e3 * inv);
}

// ---- fused wfin = Wc @ (attn @ Wv) per (e-tile, batch) block ----
__global__ __launch_bounds__(256) void mwfuse(const u16* __restrict__ attnb,
                                              const u16* __restrict__ wvtb,
                                              const u16* __restrict__ wcb,
                                              u16* __restrict__ wfin) {
  __shared__ u16 lds[25088];           // union, 50 KB
  const int M1OFF = 0;                 // m1T [64][264]
  const int A2OFF = 16896;             // Wc tile [256][32]
  const int B1OFF = 0;                 // phase1 attn [256][64]
  const int A1OFF = 16384;             // phase1 WvT [64][64]
  const int e0 = blockIdx.x * 64;
  const int b = blockIdx.y;
  const int t = threadIdx.x;
  const int wid = t >> 6, lane = t & 63;
  const int srow = t >> 3, slot = t & 7;
  const u16* attn = attnb + (long)b * 65536;

  fx4 acc[4][4] = {};
  for (int kt = 0; kt < 256; kt += 64) {
#pragma unroll
    for (int i = 0; i < 8; ++i) {
      const int row = i * 32 + srow;
      const int kq = slot ^ (row & 7);
      GLOAD(attn + (long)row * 256 + kt + kq * 8, &lds[B1OFF + i * 2048 + wid * 512]);
    }
#pragma unroll
    for (int i = 0; i < 2; ++i) {
      const int row = i * 32 + srow;
      const int kq = slot ^ (row & 7);
      GLOAD(wvtb + (long)(e0 + row) * 256 + kt + kq * 8, &lds[A1OFF + i * 2048 + wid * 512]);
    }
    __syncthreads();
#pragma unroll
    for (int ko = 0; ko < 2; ++ko) {
      bf8 af[4], bfr[4];
      const int kq = ko * 4 + (lane >> 4);
#pragma unroll
      for (int f = 0; f < 4; ++f) {
        const int ar = f * 16 + (lane & 15);
        af[f] = *(const bf8*)&lds[A1OFF + ar * 64 + ((kq ^ (ar & 7)) * 8)];
        const int br = wid * 64 + f * 16 + (lane & 15);
        bfr[f] = *(const bf8*)&lds[B1OFF + br * 64 + ((kq ^ (br & 7)) * 8)];
      }
#pragma unroll
      for (int fm = 0; fm < 4; ++fm)
#pragma unroll
        for (int fn = 0; fn < 4; ++fn)
          acc[fm][fn] = __builtin_amdgcn_mfma_f32_16x16x32_bf16(af[fm], bfr[fn], acc[fm][fn], 0, 0, 0);
    }
    __syncthreads();
  }
#pragma unroll
  for (int fm = 0; fm < 4; ++fm) {
    const int ep0 = fm * 16 + ((lane >> 4) << 2);
#pragma unroll
    for (int fn = 0; fn < 4; ++fn) {
      const int c = wid * 64 + fn * 16 + (lane & 15);
#pragma unroll
      for (int r = 0; r < 4; ++r)
        lds[M1OFF + (ep0 + r) * 264 + c] = f2b(acc[fm][fn][r]);
    }
  }
  __syncthreads();
  fx4 acc2[4][4] = {};
  for (int kt = 0; kt < 256; kt += 32) {
#pragma unroll
    for (int i = 0; i < 4; ++i) {
      const int row = i * 64 + (t >> 2);
      const int kq = (t & 3) ^ (row & 3);
      GLOAD(wcb + (long)row * 256 + kt + kq * 8, &lds[A2OFF + i * 2048 + wid * 512]);
    }
    __syncthreads();
    bf8 af[4], bfr[4];
    const int kq = lane >> 4;
#pragma unroll
    for (int f = 0; f < 4; ++f) {
      const int ar = wid * 64 + f * 16 + (lane & 15);
      af[f] = *(const bf8*)&lds[A2OFF + ar * 32 + ((kq ^ (ar & 3)) * 8)];
      const int br = f * 16 + (lane & 15);
      bfr[f] = *(const bf8*)&lds[M1OFF + br * 264 + kt + kq * 8];
    }
#pragma unroll
    for (int fm = 0; fm < 4; ++fm)
#pragma unroll
      for (int fn = 0; fn < 4; ++fn)
        acc2[fm][fn] = __builtin_amdgcn_mfma_f32_16x16x32_bf16(af[fm], bfr[fn], acc2[fm][fn], 0, 0, 0);
    __syncthreads();
  }
  u16* wf = wfin + (long)b * 65536;
#pragma unroll
  for (int fm = 0; fm < 4; ++fm) {
    const int o0 = wid * 64 + fm * 16 + ((lane >> 4) << 2);
#pragma unroll
    for (int fn = 0; fn < 4; ++fn) {
      const int e = e0 + fn * 16 + (lane & 15);
#pragma unroll
      for (int r = 0; r < 4; ++r)
        wf[(long)(o0 + r) * 256 + e] = f2b(acc2[fm][fn][r]);
    }
  }
}

// ---- SE gates from column-sum partials + wfin matvec + 2-layer MLP ----
__global__ __launch_bounds__(256) void sefuse(const float* __restrict__ cspart,
                                              const u16* __restrict__ wfin,
                                              const float* __restrict__ bcb,
                                              const float* __restrict__ w1d, const float* __restrict__ w2d,
                                              const float* __restrict__ w1s, const float* __restrict__ w2s,
                                              float* __restrict__ gd, float* __restrict__ gs) {
  const int b = blockIdx.x;
  const int t = threadIdx.x;
  __shared__ float xm[256], p[256], hd[16], hs[16];
  float s = 0.f;
#pragma unroll 8
  for (int sl = 0; sl < 128; ++sl) s += cspart[(long)sl * 2048 + b * 256 + t];
  xm[t] = s;
  __syncthreads();
  const u16* wf = wfin + (long)b * 65536 + (long)t * 256;
  float acc = 0.f;
#pragma unroll 4
  for (int e = 0; e < 256; e += 8) {
    const s8v w8 = *(const s8v*)&wf[e];
    const fx4 x0v = *(const fx4*)&xm[e];
    const fx4 x1v = *(const fx4*)&xm[e + 4];
#pragma unroll
    for (int j = 0; j < 4; ++j) {
      acc += b2f((u16)w8[j]) * x0v[j];
      acc += b2f((u16)w8[4 + j]) * x1v[j];
    }
  }
  p[t] = acc * (1.f / 4096.f) + bcb[t];
  __syncthreads();
  if (t < 16) {
    float ad = 0.f, as2 = 0.f;
    for (int j = 0; j < 256; ++j) {
      ad += w1d[t * 256 + j] * p[j];
      as2 += w1s[t * 256 + j] * p[j];
    }
    hd[t] = fmaxf(ad, 0.f);
    hs[t] = fmaxf(as2, 0.f);
  }
  __syncthreads();
  float ad = 0.f, as2 = 0.f;
#pragma unroll
  for (int r = 0; r < 16; ++r) {
    ad += w2d[t * 16 + r] * hd[r];
    as2 += w2s[t * 16 + r] * hs[r];
  }
  gd[b * 256 + t] = 1.f / (1.f + __expf(-ad));
  gs[b * 256 + t] = 1.f / (1.f + __expf(-as2));
}

extern "C" void kernel_launch(void* const* d_in, const int* in_sizes, int n_in,
                              void* d_out, int out_size, void* d_ws, size_t ws_size,
                              hipStream_t stream) {
  const float* fd  = (const float*)d_in[0];
  const float* fs  = (const float*)d_in[1];
  const float* W0  = (const float*)d_in[2];
  const float* Wdw = (const float*)d_in[3];
  const float* Wq  = (const float*)d_in[4];
  const float* Wk  = (const float*)d_in[5];
  const float* Wv  = (const float*)d_in[6];
  const float* Wp  = (const float*)d_in[7];
  const float* bp  = (const float*)d_in[8];
  const float* Wsp = (const float*)d_in[9];
  const float* w1d = (const float*)d_in[10];
  const float* w2d = (const float*)d_in[11];
  const float* w1s = (const float*)d_in[12];
  const float* w2s = (const float*)d_in[13];

  char* ws = (char*)d_ws;
  u16* x0b    = (u16*)(ws + 0);            // [B,N,256] 16.7MB; dead after dwconvT
  u16* xtb    = (u16*)(ws + 16777216);     // [B,N,256] 16.7MB; live to final gemm
  u16* xtT    = (u16*)(ws + 33554432);     // [B,256,N] 16.7MB; dead after gram
  float* part = (float*)(ws + 50331648);   // [8][B,256,256] fp32 16.7MB
  u16* G2     = (u16*)(ws + 67108864);     // [B,256,512] hi|lo 2.1MB
  u16* S2     = (u16*)(ws + 69206016);     // [B,256,512] hi|lo 2.1MB
  float* araw = (float*)(ws + 71303168);   // [2][B,256,256] fp32 4.2MB (split-K pair)
  u16* attnb  = (u16*)(ws + 75497472);     // [B,256,256] 1MB
  u16* wfin   = (u16*)(ws + 76546048);     // [B,256,256] 1MB
  u16* w0b    = (u16*)(ws + 77594624);     // [256,512] 256KB
  u16* wqk2   = (u16*)(ws + 77856768);     // [512,512] 512KB
  u16* wvtb   = (u16*)(ws + 78381056);     // [256,256] 128KB
  u16* wcb    = (u16*)(ws + 78512128);     // [256,256] 128KB
  float* bcb  = (float*)(ws + 78643200);   // 256
  float* dpart = (float*)(ws + 78644224);  // [4][B*512] fp32 64KB
  float* cspart = (float*)(ws + 78709760); // [128][B*256] fp32 1MB
  float* gdp  = (float*)(ws + 79758336);   // [B,256]
  float* gsp  = (float*)(ws + 79766528);   // [B,256]
  float* od   = (float*)d_out;

  prep<<<dim3(2048, 4), 256, 0, stream>>>(W0, Wq, Wk, Wv, Wsp, Wp, bp,
                                          w0b, wqk2, wvtb, wcb, bcb);
  conv0f<<<dim3(64, 8), 512, 0, stream>>>(fd, fs, w0b, x0b);
  dwconvT<<<1024, 256, 0, stream>>>(x0b, Wdw, xtb, xtT, cspart);
  // Gram: G[b,c,e] = sum_n xtT[b,c,n] xtT[b,e,n]   M=N=256 K=4096, split-K x8
  gemm_nt<float, 0, 0><<<dim3(2, 2, 64), 256, 0, stream>>>(
      xtT, 1048576, 4096, xtT, 1048576, 4096,
      part, 65536, 524288, 256, nullptr, 512, 8, nullptr, nullptr, nullptr, nullptr);
  gsplit<<<512, 256, 0, stream>>>(part, G2);
  // SS = Wqk @ G  (M=512 N=256 K=512 hi|lo) with fused S2-split + diag partials
  gemm_nt<u16, 0, 1><<<dim3(4, 2, 8), 256, 0, stream>>>(
      wqk2, 0, 512, G2, 131072, 512, S2, 131072, 0, 512, nullptr, 512, 1,
      Wq, Wk, dpart, nullptr);
  // araw = Wk G Wq^T: A=[Wk|Wk], B=S2 hi|lo   M=N=256, split-K x2 over hi/lo
  gemm_nt<float, 0, 0><<<dim3(2, 2, 16), 256, 0, stream>>>(
      wqk2 + 131072, 0, 512, S2, 131072, 512, araw, 65536, 524288, 256,
      nullptr, 256, 2, nullptr, nullptr, nullptr, nullptr);
  softmax_g2<<<512, 256, 0, stream>>>(araw, dpart, attnb);
  // wfin = Wc @ attn @ Wv (fused two-stage)
  mwfuse<<<dim3(4, 8), 256, 0, stream>>>(attnb, wvtb, wcb, wfin);
  // SE gates from linearity: pool = Wfin @ colsum(xt)/4096 + bc
  sefuse<<<8, 256, 0, stream>>>(cspart, wfin, bcb, w1d, w2d, w1s, w2s, gdp, gsp);
  // final: od/os[b,o,n] = (sum_e wfin[b,o,e] xt[b,n,e] + bc[o])*g + residual
  gemm_nt<float, 0, 4><<<dim3(2, 32, 8), 256, 0, stream>>>(
      wfin, 65536, 256, xtb, 1048576, 256, od, 1048576, 0, 4096, bcb, 256, 1,
      fd, fs, gdp, gsp);
}